// Round 5
// baseline (224.090 us; speedup 1.0000x reference)
//
#include <hip/hip_runtime.h>
#include <hip/hip_bf16.h>
#include <cstdint>
#include <cstddef>

typedef __hip_bfloat16 bf16;
typedef float  floatx4 __attribute__((ext_vector_type(4)));
typedef __bf16 bf16x8  __attribute__((ext_vector_type(8)));

typedef __attribute__((address_space(1))) void as1_void;
typedef __attribute__((address_space(3))) void as3_void;

constexpr int Bn = 4, Ln = 2048, Cn = 1024;

__device__ __forceinline__ void store_one(float* p, float v) { *p = v; }
__device__ __forceinline__ void store_one(bf16*  p, float v) { *p = __float2bfloat16(v); }

// ---------------------------------------------------------------------------
// LESSONS LEDGER
// R1: T2 swizzle verified (SQ_LDS_BANK_CONFLICT == 0); 256^2 core ~4.7 TF/CU.
// R2: NO intra-kernel cross-block sync (fence+spin = coherence storm, +90us).
// R3: NO bulk fp32 global atomics (16.8M adds ~ +20us tax).
// R4: top dispatches are now the harness's 256MiB ws re-poison fills (~40us,
//     82% HBM) — fixed overhead. Remaining controllable slack = intra-wave
//     imbalance (PV wall 32 vs mean 18; VWT wave half-idle). R5 fixes both
//     with M=128 sibling cores: uniform paired PV tiles + VWT-256-way+sm.
// ---------------------------------------------------------------------------
#define BAR()    asm volatile("s_barrier" ::: "memory")
#define VMCNT2() asm volatile("s_waitcnt vmcnt(2)" ::: "memory")
#define VMCNT0() asm volatile("s_waitcnt vmcnt(0)" ::: "memory")
#define SCHEDB() __builtin_amdgcn_sched_barrier(0)
#define STAGE(gp, off) \
    __builtin_amdgcn_global_load_lds((const as1_void*)(gp), (as3_void*)(smem + (off)), 16, 0, 0)

// ---------------------------------------------------------------------------
// 256x256 core (verified R1-R4): BK=64, 8 waves (2Mx4N), counted vmcnt(2).
// ---------------------------------------------------------------------------
__device__ __forceinline__ void gemm256_core(
    char* __restrict__ smem,
    const bf16* __restrict__ A, const bf16* __restrict__ B,
    int m0, int n0, int kbeg, int kend, int lda, int ldb,
    floatx4 (&acc)[8][4])
{
    const int tid  = threadIdx.x;
    const int lane = tid & 63;
    const int quad = lane >> 4;
    const int lr   = lane & 15;
    const int wave = tid >> 6;
    const int wm   = (wave >> 2) * 128;
    const int wn   = (wave & 3) * 64;

#pragma unroll
    for (int i = 0; i < 8; ++i)
#pragma unroll
        for (int j = 0; j < 4; ++j) { floatx4 z = {0.f, 0.f, 0.f, 0.f}; acc[i][j] = z; }

    const int srow = tid >> 3;
    const int sx   = (tid & 7) ^ (srow & 7);
    const bf16* gA = A + (size_t)(m0 + srow) * lda + sx * 8 + kbeg;
    const bf16* gB = B + (size_t)(n0 + srow) * ldb + sx * 8 + kbeg;
    const int wuni = __builtin_amdgcn_readfirstlane((tid & 0x1C0) * 16);

    const int aoff = (wm + lr) * 64;
    const int boff = (wn + lr) * 64;
    const int s0   = (quad ^ (lr & 7)) * 8;

    const int NT = (kend - kbeg) >> 6;

    STAGE(gB,             32768 + 0 * 8192 + wuni);
    STAGE(gB + 64  * ldb, 32768 + 1 * 8192 + wuni);
    STAGE(gB + 128 * ldb, 32768 + 2 * 8192 + wuni);
    STAGE(gB + 192 * ldb, 32768 + 3 * 8192 + wuni);
    STAGE(gA,                     0 * 8192 + wuni);
    STAGE(gA + 128 * lda,         2 * 8192 + wuni);
    STAGE(gA + 64  * lda,         1 * 8192 + wuni);
    STAGE(gA + 192 * lda,         3 * 8192 + wuni);
    VMCNT2();
    BAR();

#define LDA4(MB, SK) do { _Pragma("unroll") for (int ii = 0; ii < 4; ++ii) \
        a[ii] = *(const bf16x8*)(As + aoff + ((MB) * 4 + ii) * 1024 + (SK)); } while (0)
#define LDB4(SK) do { _Pragma("unroll") for (int nn = 0; nn < 4; ++nn) \
        b[nn] = *(const bf16x8*)(Bs + boff + nn * 1024 + (SK)); } while (0)
#define MFMA16(MB) do { _Pragma("unroll") for (int ii = 0; ii < 4; ++ii) { \
        _Pragma("unroll") for (int nn = 0; nn < 4; ++nn) \
            acc[(MB) * 4 + ii][nn] = __builtin_amdgcn_mfma_f32_16x16x32_bf16( \
                a[ii], b[nn], acc[(MB) * 4 + ii][nn], 0, 0, 0); } } while (0)

    for (int t = 0; t < NT; ++t) {
        const bf16* As = (const bf16*)(smem + (t & 1) * 65536);
        const bf16* Bs = (const bf16*)(smem + (t & 1) * 65536 + 32768);
        const int  wl  = ((t + 1) & 1) * 65536;
        const int  kn  = (t + 1) << 6;
        const bool more = (t + 1 < NT);
        bf16x8 a[4], b[4];

        LDB4(s0);
        LDA4(0, s0);
        if (more) {
            STAGE(gB + kn,            wl + 32768 + 0 * 8192 + wuni);
            STAGE(gB + kn + 64 * ldb, wl + 32768 + 1 * 8192 + wuni);
        }
        BAR(); SCHEDB();
        __builtin_amdgcn_s_setprio(1);
        MFMA16(0);
        __builtin_amdgcn_s_setprio(0);
        SCHEDB();
        if (more) VMCNT2(); else VMCNT0();
        BAR();

        LDA4(1, s0);
        if (more) {
            STAGE(gB + kn + 128 * ldb, wl + 32768 + 2 * 8192 + wuni);
            STAGE(gB + kn + 192 * ldb, wl + 32768 + 3 * 8192 + wuni);
        }
        BAR(); SCHEDB();
        __builtin_amdgcn_s_setprio(1);
        MFMA16(1);
        __builtin_amdgcn_s_setprio(0);
        SCHEDB();
        BAR();

        LDB4(s0 ^ 32);
        LDA4(0, s0 ^ 32);
        if (more) {
            STAGE(gA + kn,             wl + 0 * 8192 + wuni);
            STAGE(gA + kn + 128 * lda, wl + 2 * 8192 + wuni);
        }
        BAR(); SCHEDB();
        __builtin_amdgcn_s_setprio(1);
        MFMA16(0);
        __builtin_amdgcn_s_setprio(0);
        SCHEDB();
        BAR();

        LDA4(1, s0 ^ 32);
        if (more) {
            STAGE(gA + kn + 64  * lda, wl + 1 * 8192 + wuni);
            STAGE(gA + kn + 192 * lda, wl + 3 * 8192 + wuni);
        }
        BAR(); SCHEDB();
        __builtin_amdgcn_s_setprio(1);
        MFMA16(1);
        __builtin_amdgcn_s_setprio(0);
        SCHEDB();
        if (more) VMCNT2();
        BAR();
    }
#undef LDA4
#undef LDB4
#undef MFMA16
}

template <typename OutT>
__device__ __forceinline__ void gemm256(
    char* __restrict__ smem,
    const bf16* __restrict__ A, const bf16* __restrict__ B, OutT* __restrict__ C,
    int m0, int n0, int kbeg, int kend, int lda, int ldb, int ldc, float cscale)
{
    floatx4 acc[8][4];
    gemm256_core(smem, A, B, m0, n0, kbeg, kend, lda, ldb, acc);

    const int lane = threadIdx.x & 63;
    const int quad = lane >> 4;
    const int lr   = lane & 15;
    const int wave = threadIdx.x >> 6;
    const int wm   = (wave >> 2) * 128;
    const int wn   = (wave & 3) * 64;

#pragma unroll
    for (int mi = 0; mi < 8; ++mi) {
        const int row = m0 + wm + mi * 16 + quad * 4;
#pragma unroll
        for (int n = 0; n < 4; ++n) {
            const int col = n0 + wn + n * 16 + lr;
            OutT* cp = C + (size_t)row * ldc + col;
#pragma unroll
            for (int r = 0; r < 4; ++r)
                store_one(cp + (size_t)r * ldc, acc[mi][n][r] * cscale);
        }
    }
}

// ---------------------------------------------------------------------------
// R5 sibling core #1: 128(M) x 256(N), BK=64. 8 waves: 2M(64 rows) x 4N(64).
// Phases by mi-pair {01,23} x kk. A = 2 units (16KB), B = 4 (32KB); BUF 48KB.
// Ledger: phase A spans both A-halves across waves -> every unit needed at A;
// prologue vmcnt(0); per-tile issue B01@A, B23@B, A01@C; single vmcnt(0) at
// end-D (4-6 loads in flight across the 3 interior barriers).
// ---------------------------------------------------------------------------
__device__ __forceinline__ void gemm_m128n256(
    char* __restrict__ smem,
    const bf16* __restrict__ A, const bf16* __restrict__ B, bf16* __restrict__ C,
    int m0, int n0, int kend, int lda, int ldb, int ldc)
{
    const int tid  = threadIdx.x;
    const int lane = tid & 63;
    const int quad = lane >> 4;
    const int lr   = lane & 15;
    const int wave = tid >> 6;
    const int wm   = (wave >> 2) * 64;    // 2 waves along M, 64 rows each
    const int wn   = (wave & 3) * 64;     // 4 waves along N

    floatx4 acc[4][4];
#pragma unroll
    for (int i = 0; i < 4; ++i)
#pragma unroll
        for (int j = 0; j < 4; ++j) { floatx4 z = {0.f, 0.f, 0.f, 0.f}; acc[i][j] = z; }

    const int srow = tid >> 3;
    const int sx   = (tid & 7) ^ (srow & 7);
    const bf16* gA = A + (size_t)(m0 + srow) * lda + sx * 8;
    const bf16* gB = B + (size_t)(n0 + srow) * ldb + sx * 8;
    const int wuni = __builtin_amdgcn_readfirstlane((tid & 0x1C0) * 16);

    const int aoff = (wm + lr) * 64;
    const int boff = (wn + lr) * 64;
    const int s0   = (quad ^ (lr & 7)) * 8;

    const int NT  = kend >> 6;
    const int BUF = 49152;                // 16KB A + 32KB B

    STAGE(gA,             0 * 8192 + wuni);
    STAGE(gA + 64 * lda,  1 * 8192 + wuni);
    STAGE(gB,             16384 + 0 * 8192 + wuni);
    STAGE(gB + 64  * ldb, 16384 + 1 * 8192 + wuni);
    STAGE(gB + 128 * ldb, 16384 + 2 * 8192 + wuni);
    STAGE(gB + 192 * ldb, 16384 + 3 * 8192 + wuni);
    VMCNT0();
    BAR();

#define LDA2(PH, SK) do { _Pragma("unroll") for (int ii = 0; ii < 2; ++ii) \
        a[ii] = *(const bf16x8*)(As + aoff + ((PH) * 2 + ii) * 1024 + (SK)); } while (0)
#define LDB4(SK) do { _Pragma("unroll") for (int nn = 0; nn < 4; ++nn) \
        b[nn] = *(const bf16x8*)(Bs + boff + nn * 1024 + (SK)); } while (0)
#define MFMA8(PH) do { _Pragma("unroll") for (int ii = 0; ii < 2; ++ii) { \
        _Pragma("unroll") for (int nn = 0; nn < 4; ++nn) \
            acc[(PH) * 2 + ii][nn] = __builtin_amdgcn_mfma_f32_16x16x32_bf16( \
                a[ii], b[nn], acc[(PH) * 2 + ii][nn], 0, 0, 0); } } while (0)

    for (int t = 0; t < NT; ++t) {
        const bf16* As = (const bf16*)(smem + (t & 1) * BUF);
        const bf16* Bs = (const bf16*)(smem + (t & 1) * BUF + 16384);
        const int  wl  = ((t + 1) & 1) * BUF;
        const int  kn  = (t + 1) << 6;
        const bool more = (t + 1 < NT);
        bf16x8 a[2], b[4];

        // phase A: mi 0-1, kk0
        LDB4(s0);
        LDA2(0, s0);
        if (more) {
            STAGE(gB + kn,            wl + 16384 + 0 * 8192 + wuni);
            STAGE(gB + kn + 64 * ldb, wl + 16384 + 1 * 8192 + wuni);
        }
        BAR(); SCHEDB();
        __builtin_amdgcn_s_setprio(1);
        MFMA8(0);
        __builtin_amdgcn_s_setprio(0);
        SCHEDB();
        BAR();

        // phase B: mi 2-3, kk0
        LDA2(1, s0);
        if (more) {
            STAGE(gB + kn + 128 * ldb, wl + 16384 + 2 * 8192 + wuni);
            STAGE(gB + kn + 192 * ldb, wl + 16384 + 3 * 8192 + wuni);
        }
        BAR(); SCHEDB();
        __builtin_amdgcn_s_setprio(1);
        MFMA8(1);
        __builtin_amdgcn_s_setprio(0);
        SCHEDB();
        BAR();

        // phase C: mi 0-1, kk1
        LDB4(s0 ^ 32);
        LDA2(0, s0 ^ 32);
        if (more) {
            STAGE(gA + kn,            wl + 0 * 8192 + wuni);
            STAGE(gA + kn + 64 * lda, wl + 1 * 8192 + wuni);
        }
        BAR(); SCHEDB();
        __builtin_amdgcn_s_setprio(1);
        MFMA8(0);
        __builtin_amdgcn_s_setprio(0);
        SCHEDB();
        BAR();

        // phase D: mi 2-3, kk1
        LDA2(1, s0 ^ 32);
        BAR(); SCHEDB();
        __builtin_amdgcn_s_setprio(1);
        MFMA8(1);
        __builtin_amdgcn_s_setprio(0);
        SCHEDB();
        if (more) VMCNT0();
        BAR();
    }
#undef LDA2
#undef LDB4
#undef MFMA8

#pragma unroll
    for (int mi = 0; mi < 4; ++mi) {
        const int row = m0 + wm + mi * 16 + quad * 4;
#pragma unroll
        for (int n = 0; n < 4; ++n) {
            const int col = n0 + wn + n * 16 + lr;
            bf16* cp = C + (size_t)row * ldc + col;
#pragma unroll
            for (int r = 0; r < 4; ++r)
                store_one(cp + (size_t)r * ldc, acc[mi][n][r]);
        }
    }
}

// ---------------------------------------------------------------------------
// R5 sibling core #2: 128(M) x 128(N), BK=64, fp32 out. 8 waves: 2M x 4N(32).
// A = 2 units, B = 2 units; BUF 32KB (64KB LDS). Same single end-D vmcnt(0).
// ---------------------------------------------------------------------------
__device__ __forceinline__ void gemm_m128n128(
    char* __restrict__ smem,
    const bf16* __restrict__ A, const bf16* __restrict__ B, float* __restrict__ C,
    int m0, int n0, int kend, int lda, int ldb, int ldc)
{
    const int tid  = threadIdx.x;
    const int lane = tid & 63;
    const int quad = lane >> 4;
    const int lr   = lane & 15;
    const int wave = tid >> 6;
    const int wm   = (wave >> 2) * 64;
    const int wn   = (wave & 3) * 32;

    floatx4 acc[4][2];
#pragma unroll
    for (int i = 0; i < 4; ++i)
#pragma unroll
        for (int j = 0; j < 2; ++j) { floatx4 z = {0.f, 0.f, 0.f, 0.f}; acc[i][j] = z; }

    const int srow = tid >> 3;
    const int sx   = (tid & 7) ^ (srow & 7);
    const bf16* gA = A + (size_t)(m0 + srow) * lda + sx * 8;
    const bf16* gB = B + (size_t)(n0 + srow) * ldb + sx * 8;
    const int wuni = __builtin_amdgcn_readfirstlane((tid & 0x1C0) * 16);

    const int aoff = (wm + lr) * 64;
    const int boff = (wn + lr) * 64;
    const int s0   = (quad ^ (lr & 7)) * 8;

    const int NT  = kend >> 6;
    const int BUF = 32768;

    STAGE(gA,            0 * 8192 + wuni);
    STAGE(gA + 64 * lda, 1 * 8192 + wuni);
    STAGE(gB,            16384 + 0 * 8192 + wuni);
    STAGE(gB + 64 * ldb, 16384 + 1 * 8192 + wuni);
    VMCNT0();
    BAR();

#define LDA2(PH, SK) do { _Pragma("unroll") for (int ii = 0; ii < 2; ++ii) \
        a[ii] = *(const bf16x8*)(As + aoff + ((PH) * 2 + ii) * 1024 + (SK)); } while (0)
#define LDB2(SK) do { _Pragma("unroll") for (int nn = 0; nn < 2; ++nn) \
        b[nn] = *(const bf16x8*)(Bs + boff + nn * 1024 + (SK)); } while (0)
#define MFMA4(PH) do { _Pragma("unroll") for (int ii = 0; ii < 2; ++ii) { \
        _Pragma("unroll") for (int nn = 0; nn < 2; ++nn) \
            acc[(PH) * 2 + ii][nn] = __builtin_amdgcn_mfma_f32_16x16x32_bf16( \
                a[ii], b[nn], acc[(PH) * 2 + ii][nn], 0, 0, 0); } } while (0)

    for (int t = 0; t < NT; ++t) {
        const bf16* As = (const bf16*)(smem + (t & 1) * BUF);
        const bf16* Bs = (const bf16*)(smem + (t & 1) * BUF + 16384);
        const int  wl  = ((t + 1) & 1) * BUF;
        const int  kn  = (t + 1) << 6;
        const bool more = (t + 1 < NT);
        bf16x8 a[2], b[2];

        // phase A: mi 0-1, kk0
        LDB2(s0);
        LDA2(0, s0);
        if (more) {
            STAGE(gB + kn,            wl + 16384 + 0 * 8192 + wuni);
            STAGE(gB + kn + 64 * ldb, wl + 16384 + 1 * 8192 + wuni);
        }
        BAR(); SCHEDB();
        __builtin_amdgcn_s_setprio(1);
        MFMA4(0);
        __builtin_amdgcn_s_setprio(0);
        SCHEDB();
        BAR();

        // phase B: mi 2-3, kk0
        LDA2(1, s0);
        if (more) {
            STAGE(gA + kn,            wl + 0 * 8192 + wuni);
            STAGE(gA + kn + 64 * lda, wl + 1 * 8192 + wuni);
        }
        BAR(); SCHEDB();
        __builtin_amdgcn_s_setprio(1);
        MFMA4(1);
        __builtin_amdgcn_s_setprio(0);
        SCHEDB();
        BAR();

        // phase C: mi 0-1, kk1
        LDB2(s0 ^ 32);
        LDA2(0, s0 ^ 32);
        BAR(); SCHEDB();
        __builtin_amdgcn_s_setprio(1);
        MFMA4(0);
        __builtin_amdgcn_s_setprio(0);
        SCHEDB();
        BAR();

        // phase D: mi 2-3, kk1
        LDA2(1, s0 ^ 32);
        BAR(); SCHEDB();
        __builtin_amdgcn_s_setprio(1);
        MFMA4(1);
        __builtin_amdgcn_s_setprio(0);
        SCHEDB();
        if (more) VMCNT0();
        BAR();
    }
#undef LDA2
#undef LDB2
#undef MFMA4

#pragma unroll
    for (int mi = 0; mi < 4; ++mi) {
        const int row = m0 + wm + mi * 16 + quad * 4;
#pragma unroll
        for (int n = 0; n < 2; ++n) {
            const int col = n0 + wn + n * 16 + lr;
            float* cp = C + (size_t)row * ldc + col;
#pragma unroll
            for (int r = 0; r < 4; ++r)
                cp[(size_t)r * ldc] = acc[mi][n][r];
        }
    }
}

// ---------------------------------------------------------------------------
// g1: QK = Xb . Wqkb^T  (8192x2048, K=1024) -> 32x8 = 256 blocks
// ---------------------------------------------------------------------------
__global__ __launch_bounds__(512, 2)
void g1_qk(const bf16* __restrict__ Xb, const bf16* __restrict__ Wqkb,
           bf16* __restrict__ QK)
{
    __shared__ __align__(16) char smem[131072];
    const int i = blockIdx.x;
    const int j = i >> 3;
    const int mt = (i & 7) * 4 + (j & 3);
    const int nt = j >> 2;
    gemm256<bf16>(smem, Xb, Wqkb, QK, mt * 256, nt * 256, 0, 1024, 1024, 1024, 2048, 1.0f);
}

// ---------------------------------------------------------------------------
// g2: blocks [0,144)  -> S = (Q.K^T)/32, triangular 256-tiles, 36/batch.
//     blocks [144,160) -> W2 = Wo.Wv (1024^2, K=1024).
// ---------------------------------------------------------------------------
__global__ __launch_bounds__(512, 2)
void g2_s_w2(const bf16* __restrict__ QK, const bf16* __restrict__ Wob,
             const bf16* __restrict__ WvT, bf16* __restrict__ S,
             bf16* __restrict__ W2)
{
    __shared__ __align__(16) char smem[131072];
    const int i = blockIdx.x;
    if (i < 144) {
        const int b = (i & 7) >> 1;
        const int t = (i >> 3) * 2 + (i & 1);        // 0..35
        int ti = (int)((sqrtf(8.f * t + 1.f) - 1.f) * 0.5f);
        while ((ti + 1) * (ti + 2) / 2 <= t) ++ti;
        while (ti * (ti + 1) / 2 > t) --ti;
        const int tj = t - ti * (ti + 1) / 2;
        const bf16* Aq = QK + (size_t)b * Ln * 2048;
        const bf16* Bk = Aq + 1024;
        bf16* Sb = S + (size_t)b * Ln * Ln;
        gemm256<bf16>(smem, Aq, Bk, Sb, ti * 256, tj * 256, 0, 1024, 2048, 2048, Ln, 0.03125f);
    } else {
        const int j = i - 144;
        gemm256<bf16>(smem, Wob, WvT, W2, (j & 3) * 256, (j >> 2) * 256, 0, 1024, 1024, 1024, 1024, 1.0f);
    }
}

// ---------------------------------------------------------------------------
// softmax: 32 rows per block (8 waves x 4 rows), no barriers.
// ---------------------------------------------------------------------------
__device__ __forceinline__ float waveMax(float x) {
#pragma unroll
    for (int o = 32; o > 0; o >>= 1) x = fmaxf(x, __shfl_xor(x, o, 64));
    return x;
}
__device__ __forceinline__ float waveSum(float x) {
#pragma unroll
    for (int o = 32; o > 0; o >>= 1) x += __shfl_xor(x, o, 64);
    return x;
}

__device__ void softmax_rows32(bf16* __restrict__ S, int row0)
{
    const int wave = threadIdx.x >> 6, lane = threadIdx.x & 63;
    for (int it4 = 0; it4 < 4; ++it4) {
        const int row = row0 + wave * 4 + it4;       // 0..8191 = b*L + q
        const int q = row & (Ln - 1);
        bf16* Srow = S + (size_t)row * Ln;
        const int kmax = ((q >> 7) + 1) << 7;
        const int nv = (kmax + 511) >> 9;            // 1..4 chunks of 512 cols
        float x[4][8];
        float m = -1e30f;
        for (int it = 0; it < nv; ++it) {
            int c0 = it * 512 + lane * 8;
            bf16x8 v = *(const bf16x8*)(Srow + c0);
#pragma unroll
            for (int e = 0; e < 8; ++e) {
                float f = (float)v[e];
                f = (c0 + e <= q) ? f : -1e30f;
                x[it][e] = f;
                m = fmaxf(m, f);
            }
        }
        m = waveMax(m);
        float s = 0.f;
        for (int it = 0; it < nv; ++it)
#pragma unroll
            for (int e = 0; e < 8; ++e) {
                float ex = (x[it][e] > -1e29f) ? __expf(x[it][e] - m) : 0.f;
                x[it][e] = ex;
                s += ex;
            }
        s = waveSum(s);
        const float inv = 1.f / s;
        for (int it = 0; it < nv; ++it) {
            bf16x8 o;
#pragma unroll
            for (int e = 0; e < 8; ++e) o[e] = (__bf16)(x[it][e] * inv);
            *(bf16x8*)(Srow + it * 512 + lane * 8) = o;
        }
    }
}

// ---------------------------------------------------------------------------
// g3: 256 blocks. Each: VWT M128xN256 tile (8 mh x 32 nt) + 32 softmax rows.
// XCD i&7 owns an nt-group of 4 (Xb B-panel L2-local).
// Wall = VWT half-tile (~16-17us) + sm slice (~5us) ~= 22 (was 28).
// ---------------------------------------------------------------------------
__global__ __launch_bounds__(512, 2)
void g3_vwt_sm(const bf16* __restrict__ W2, const bf16* __restrict__ Xb,
               bf16* __restrict__ VWT, bf16* __restrict__ S)
{
    __shared__ __align__(16) char smem[98304];
    const int i = blockIdx.x;
    const int j = i >> 3;
    const int nt = (i & 7) * 4 + (j & 3);            // 0..31
    const int mh = j >> 2;                           // 0..7
    gemm_m128n256(smem, W2, Xb, VWT, mh * 128, nt * 256, 1024, 1024, 1024, 8192);
    softmax_rows32(S, i * 32);
}

// ---------------------------------------------------------------------------
// g4: out = P . VW (fp32). R5: uniform paired tiles, M=128 N=128.
// Block handles (b, mh, nt) AND (b, 15-mh, nt): sum K = (mh+1 + 16-mh)*128
// = 2176 for every block -> 256 identical blocks (~71 MFLOP, ~20-22us).
// Causal: rows [mh*128, +128) need K <= (mh+1)*128; masked P cols are 0.
// ---------------------------------------------------------------------------
__global__ __launch_bounds__(512, 2)
void g4_out(const bf16* __restrict__ P, const bf16* __restrict__ VWT,
            float* __restrict__ out)
{
    __shared__ __align__(16) char smem[65536];
    const int i = blockIdx.x;                        // 256
    const int r = i & 7;                             // xcd = 2b+p
    const int b = r >> 1, p = r & 1;
    const int q = i >> 3;                            // 0..31
    const int nt = p * 4 + (q & 3);                  // 0..7
    const int mh = q >> 2;                           // 0..7 (pair with 15-mh)

    const bf16* Pp = P + (size_t)b * Ln * Ln;
    const bf16* Bv = VWT + (size_t)b * Ln;
    float* Co = out + (size_t)b * Ln * Cn;
    const int n0 = nt * 128;

    // heavy half first
    gemm_m128n128(smem, Pp, Bv, Co, (15 - mh) * 128, n0, (16 - mh) * 128, Ln, 8192, Cn);
    gemm_m128n128(smem, Pp, Bv, Co, mh * 128,        n0, (mh + 1) * 128,  Ln, 8192, Cn);
}

// ---------------------------------------------------------------------------
// cast_all: blocks [0,11264)      element-wise fp32->bf16 (X, Wqk rows, Wout)
//           blocks [11264,12288)  transpose-cast Wv (1024x1024) -> WvT
// ---------------------------------------------------------------------------
__global__ __launch_bounds__(256)
void cast_all(const float* __restrict__ X, const float* __restrict__ Wqkv,
              const float* __restrict__ Wo,
              bf16* __restrict__ Xb, bf16* __restrict__ Wqkb,
              bf16* __restrict__ Wob, bf16* __restrict__ WvT)
{
    int blk = blockIdx.x;
    if (blk < 11264) {
        int i = blk * 256 + threadIdx.x;
        const float* src; bf16* dst; int off;
        if (i < 2097152)                 { src = X;    dst = Xb;   off = i; }
        else if (i < 2097152 + 524288)   { src = Wqkv; dst = Wqkb; off = i - 2097152; }
        else                             { src = Wo;   dst = Wob;  off = i - 2621440; }
        float4 f = ((const float4*)src)[off];
        bf16 o0 = __float2bfloat16(f.x), o1 = __float2bfloat16(f.y);
        bf16 o2 = __float2bfloat16(f.z), o3 = __float2bfloat16(f.w);
        ushort4 u;
        u.x = *(unsigned short*)&o0; u.y = *(unsigned short*)&o1;
        u.z = *(unsigned short*)&o2; u.w = *(unsigned short*)&o3;
        *(ushort4*)(dst + (size_t)off * 4) = u;
    } else {
        __shared__ float t[32][33];
        int tt = blk - 11264;
        int c0 = (tt & 31) * 32;
        int r0 = (tt >> 5) * 32;
        const float* Wv = Wqkv + 2048 * 1024;
        int xcol = threadIdx.x & 31, y0 = threadIdx.x >> 5;
#pragma unroll
        for (int p = 0; p < 4; ++p) {
            int y = y0 + 8 * p;
            t[y][xcol] = Wv[(size_t)(r0 + y) * 1024 + c0 + xcol];
        }
        __syncthreads();
#pragma unroll
        for (int p = 0; p < 4; ++p) {
            int mloc = y0 + 8 * p;
            WvT[(size_t)(c0 + mloc) * 1024 + r0 + xcol] = __float2bfloat16(t[xcol][mloc]);
        }
    }
}

// ---------------------------------------------------------------------------
extern "C" void kernel_launch(void* const* d_in, const int* in_sizes, int n_in,
                              void* d_out, int out_size, void* d_ws, size_t ws_size,
                              hipStream_t stream)
{
    const float* X    = (const float*)d_in[0];   // (B,L,C)
    const float* Wqkv = (const float*)d_in[1];   // (3C,C)
    const float* Wout = (const float*)d_in[2];   // (C,C)
    float* out = (float*)d_out;                  // (B,L,C) fp32

    char* ws = (char*)d_ws;
    const size_t MiB = 1024ull * 1024ull;
    bf16* Xb   = (bf16*)(ws + 0);                // 16 MiB
    bf16* QK   = (bf16*)(ws + 16 * MiB);         // 32 MiB (q cols 0..1023, k cols 1024..2047)
    bf16* VWT  = (bf16*)(ws + 48 * MiB);         // 16 MiB (1024 x 8192, ld 8192)
    bf16* Sbuf = (bf16*)(ws + 64 * MiB);         // 32 MiB (P in place)
    bf16* Wqkb = (bf16*)(ws + 96 * MiB);         // 4 MiB
    bf16* WvT  = (bf16*)(ws + 100 * MiB);        // 2 MiB
    bf16* Wob  = (bf16*)(ws + 102 * MiB);        // 2 MiB
    bf16* W2   = (bf16*)(ws + 104 * MiB);        // 2 MiB  (total 106 MiB)

    cast_all<<<dim3(12288), 256, 0, stream>>>(X, Wqkv, Wout, Xb, Wqkb, Wob, WvT);

    g1_qk<<<dim3(256), 512, 0, stream>>>(Xb, Wqkb, QK);

    g2_s_w2<<<dim3(160), 512, 0, stream>>>(QK, Wob, WvT, Sbuf, W2);

    g3_vwt_sm<<<dim3(256), 512, 0, stream>>>(W2, Xb, VWT, Sbuf);

    g4_out<<<dim3(256), 512, 0, stream>>>(Sbuf, VWT, out);
}